// Round 1
// baseline (143.293 us; speedup 1.0000x reference)
//
#include <hip/hip_runtime.h>

#define SS 256
#define HH 1024
#define RH 512

typedef __attribute__((ext_vector_type(8))) short short8;
typedef __attribute__((ext_vector_type(4))) float f32x4;

// Convert 8 contiguous f32 -> 8 bf16 (packed, RNE) for an MFMA fragment.
__device__ __forceinline__ short8 load_frag_bf16(const float* p) {
    f32x4 lo = *reinterpret_cast<const f32x4*>(p);
    f32x4 hi = *reinterpret_cast<const f32x4*>(p + 4);
    union { int i[4]; short8 s; } u;
    asm("v_cvt_pk_bf16_f32 %0, %1, %2" : "=v"(u.i[0]) : "v"(lo.x), "v"(lo.y));
    asm("v_cvt_pk_bf16_f32 %0, %1, %2" : "=v"(u.i[1]) : "v"(lo.z), "v"(lo.w));
    asm("v_cvt_pk_bf16_f32 %0, %1, %2" : "=v"(u.i[2]) : "v"(hi.x), "v"(hi.y));
    asm("v_cvt_pk_bf16_f32 %0, %1, %2" : "=v"(u.i[3]) : "v"(hi.z), "v"(hi.w));
    return u.s;
}

// Roles by blockIdx.x:
//   [0,32):  A  = en @ W1^T   (M=256, N=512, K=1024), 64x64 tiles
//   [32,64): wd = de @ W2^T   (M=256, N=512, K=512),  64x64 tiles
//   [64,128): gates[j] = sigmoid(concat(e[t[j]], e[j]) . Wg), wave-per-j
__global__ __launch_bounds__(256) void prep_kernel(
    const float* __restrict__ en, const float* __restrict__ de,
    const int* __restrict__ target, const float* __restrict__ W1,
    const float* __restrict__ W2, const float* __restrict__ Wg,
    float* __restrict__ Aout, float* __restrict__ wdout,
    float* __restrict__ gates)
{
    const int b = blockIdx.x;
    const int tid = threadIdx.x;
    const int w = tid >> 6;
    const int lane = tid & 63;

    if (b < 64) {
        const float* X; const float* Y; float* C; int K; int tb;
        if (b < 32) { X = en; Y = W1; C = Aout;  K = HH; tb = b; }
        else        { X = de; Y = W2; C = wdout; K = RH; tb = b - 32; }
        // 64x64 tile; grid of 4 (M) x 8 (N) tiles
        const int tile_m = (tb >> 3) * 64;
        const int tile_n = (tb & 7) * 64;
        // wave quadrant: 32x32
        const int m0 = tile_m + (w >> 1) * 32;
        const int n0 = tile_n + (w & 1) * 32;
        const int fr = lane & 15;          // row/col within 16x16 frag
        const int kf = (lane >> 4) * 8;    // k offset of this lane's 8 elems

        const float* xp0 = X + (size_t)(m0 + fr) * K + kf;
        const float* xp1 = xp0 + (size_t)16 * K;
        const float* yp0 = Y + (size_t)(n0 + fr) * K + kf;
        const float* yp1 = yp0 + (size_t)16 * K;

        f32x4 acc00 = {0.f, 0.f, 0.f, 0.f};
        f32x4 acc01 = {0.f, 0.f, 0.f, 0.f};
        f32x4 acc10 = {0.f, 0.f, 0.f, 0.f};
        f32x4 acc11 = {0.f, 0.f, 0.f, 0.f};

        for (int k0 = 0; k0 < K; k0 += 32) {
            short8 a0 = load_frag_bf16(xp0 + k0);
            short8 a1 = load_frag_bf16(xp1 + k0);
            short8 b0 = load_frag_bf16(yp0 + k0);
            short8 b1 = load_frag_bf16(yp1 + k0);
            acc00 = __builtin_amdgcn_mfma_f32_16x16x32_bf16(a0, b0, acc00, 0, 0, 0);
            acc01 = __builtin_amdgcn_mfma_f32_16x16x32_bf16(a0, b1, acc01, 0, 0, 0);
            acc10 = __builtin_amdgcn_mfma_f32_16x16x32_bf16(a1, b0, acc10, 0, 0, 0);
            acc11 = __builtin_amdgcn_mfma_f32_16x16x32_bf16(a1, b1, acc11, 0, 0, 0);
        }

        // C/D layout: col = lane&15, row = (lane>>4)*4 + reg   [measured m89/m91]
        const int ccol = lane & 15;
        const int crow = (lane >> 4) * 4;
        #pragma unroll
        for (int r = 0; r < 4; r++) {
            const int rm = m0 + crow + r;
            C[(size_t)rm * RH        + n0 + ccol]      = acc00[r];
            C[(size_t)rm * RH        + n0 + 16 + ccol] = acc01[r];
            C[(size_t)(rm + 16) * RH + n0 + ccol]      = acc10[r];
            C[(size_t)(rm + 16) * RH + n0 + 16 + ccol] = acc11[r];
        }
    } else {
        // gates: one wave per j
        const int j = (b - 64) * 4 + w;
        const int tj = target[j];
        const float* e1 = en + (size_t)tj * HH;  // en_l row
        const float* e2 = en + (size_t)j * HH;
        const int h0 = lane * 16;
        float acc = 0.f;
        #pragma unroll
        for (int q = 0; q < 4; q++) {
            f32x4 a  = *reinterpret_cast<const f32x4*>(e1 + h0 + q * 4);
            f32x4 g1 = *reinterpret_cast<const f32x4*>(Wg + h0 + q * 4);
            acc += a.x * g1.x + a.y * g1.y + a.z * g1.z + a.w * g1.w;
            f32x4 c2 = *reinterpret_cast<const f32x4*>(e2 + h0 + q * 4);
            f32x4 g2 = *reinterpret_cast<const f32x4*>(Wg + HH + h0 + q * 4);
            acc += c2.x * g2.x + c2.y * g2.y + c2.z * g2.z + c2.w * g2.w;
        }
        #pragma unroll
        for (int off = 32; off > 0; off >>= 1)
            acc += __shfl_down(acc, off, 64);
        if (lane == 0)
            gates[j] = 1.f / (1.f + __expf(-acc));
    }
}

// att[i,j] = sum_r relu(A[j,r] + c[i,j]*A[t[j],r] + wd[i,r]) * V[r]
// 256 blocks, each a 16x16 (i,j) tile; one thread per output element.
__global__ __launch_bounds__(256) void att_kernel(
    const float* __restrict__ A, const float* __restrict__ wd,
    const float* __restrict__ gates, const int* __restrict__ target,
    const float* __restrict__ mask, const float* __restrict__ V,
    float* __restrict__ out)
{
    const int b = blockIdx.x;
    const int i0 = (b >> 4) << 4;
    const int j0 = (b & 15) << 4;
    const int jj = threadIdx.x & 15;
    const int ii = threadIdx.x >> 4;
    const int i = i0 + ii;
    const int j = j0 + jj;
    const int tj = target[j];
    const float c = mask[i * SS + j] * gates[j];

    const f32x4* Ar = reinterpret_cast<const f32x4*>(A + (size_t)j * RH);
    const f32x4* Br = reinterpret_cast<const f32x4*>(A + (size_t)tj * RH);
    const f32x4* Wr = reinterpret_cast<const f32x4*>(wd + (size_t)i * RH);
    const f32x4* Vr = reinterpret_cast<const f32x4*>(V);

    float acc = 0.f;
    #pragma unroll 8
    for (int q = 0; q < RH / 4; q++) {
        f32x4 a = Ar[q];
        f32x4 bb = Br[q];
        f32x4 ww = Wr[q];
        f32x4 vv = Vr[q];
        float t0 = fmaxf(a.x + c * bb.x + ww.x, 0.f);
        float t1 = fmaxf(a.y + c * bb.y + ww.y, 0.f);
        float t2 = fmaxf(a.z + c * bb.z + ww.z, 0.f);
        float t3 = fmaxf(a.w + c * bb.w + ww.w, 0.f);
        acc += t0 * vv.x + t1 * vv.y + t2 * vv.z + t3 * vv.w;
    }
    out[i * SS + j] = acc;
}

extern "C" void kernel_launch(void* const* d_in, const int* in_sizes, int n_in,
                              void* d_out, int out_size, void* d_ws, size_t ws_size,
                              hipStream_t stream) {
    const float* en     = (const float*)d_in[0];   // (1,256,1024)
    const float* de     = (const float*)d_in[1];   // (1,256,512)
    const int*   target = (const int*)  d_in[2];   // (256,)
    const float* mask_  = (const float*)d_in[3];   // (256,256)
    const float* W1     = (const float*)d_in[4];   // (512,1024)
    const float* W2     = (const float*)d_in[5];   // (512,512)
    const float* V      = (const float*)d_in[6];   // (512,)
    const float* Wg     = (const float*)d_in[7];   // (2048,)
    float* out = (float*)d_out;                    // (1,256,256)

    float* A     = (float*)d_ws;                   // 256*512 f32
    float* wd    = A + SS * RH;                    // 256*512 f32
    float* gates = wd + SS * RH;                   // 256 f32

    prep_kernel<<<128, 256, 0, stream>>>(en, de, target, W1, W2, Wg, A, wd, gates);
    att_kernel<<<256, 256, 0, stream>>>(A, wd, gates, target, mask_, V, out);
}

// Round 2
// 120.885 us; speedup vs baseline: 1.1854x; 1.1854x over previous
//
#include <hip/hip_runtime.h>

#define SS 256
#define HH 1024
#define RH 512

typedef __attribute__((ext_vector_type(8))) short short8;
typedef __attribute__((ext_vector_type(4))) float f32x4;

// Convert 8 contiguous f32 -> 8 bf16 (packed, RNE) for an MFMA fragment.
__device__ __forceinline__ short8 load_frag_bf16(const float* p) {
    f32x4 lo = *reinterpret_cast<const f32x4*>(p);
    f32x4 hi = *reinterpret_cast<const f32x4*>(p + 4);
    union { int i[4]; short8 s; } u;
    asm("v_cvt_pk_bf16_f32 %0, %1, %2" : "=v"(u.i[0]) : "v"(lo.x), "v"(lo.y));
    asm("v_cvt_pk_bf16_f32 %0, %1, %2" : "=v"(u.i[1]) : "v"(lo.z), "v"(lo.w));
    asm("v_cvt_pk_bf16_f32 %0, %1, %2" : "=v"(u.i[2]) : "v"(hi.x), "v"(hi.y));
    asm("v_cvt_pk_bf16_f32 %0, %1, %2" : "=v"(u.i[3]) : "v"(hi.z), "v"(hi.w));
    return u.s;
}

// Roles by blockIdx.x:
//   [0,128):   A  = en @ W1^T (M=256,N=512,K=1024), 32x32 block tile, 16x16/wave
//   [128,256): wd = de @ W2^T (M=256,N=512,K=512),  same tiling
//   [256,320): gates[j] = sigmoid(concat(e[t[j]], e[j]) . Wg), wave-per-j
__global__ __launch_bounds__(256) void prep_kernel(
    const float* __restrict__ en, const float* __restrict__ de,
    const int* __restrict__ target, const float* __restrict__ W1,
    const float* __restrict__ W2, const float* __restrict__ Wg,
    float* __restrict__ Aout, float* __restrict__ wdout,
    float* __restrict__ gates)
{
    const int b = blockIdx.x;
    const int tid = threadIdx.x;
    const int w = tid >> 6;
    const int lane = tid & 63;

    if (b < 256) {
        const float* X; const float* Y; float* C; int K; int tb;
        if (b < 128) { X = en; Y = W1; C = Aout;  K = HH; tb = b; }
        else         { X = de; Y = W2; C = wdout; K = RH; tb = b - 128; }
        // 32x32 block tile: 8 (M) x 16 (N) block-tiles; wave = 16x16 quadrant
        const int m0 = (tb >> 4) * 32 + (w >> 1) * 16;
        const int n0 = (tb & 15) * 32 + (w & 1) * 16;
        const int fr = lane & 15;          // row within 16-row panel
        const int kf = (lane >> 4) * 8;    // k offset of this lane's 8 elems

        const float* xp = X + (size_t)(m0 + fr) * K + kf;
        const float* yp = Y + (size_t)(n0 + fr) * K + kf;

        f32x4 acc0 = {0.f, 0.f, 0.f, 0.f};
        f32x4 acc1 = {0.f, 0.f, 0.f, 0.f};
        #pragma unroll 4
        for (int k0 = 0; k0 < K; k0 += 64) {
            short8 a0 = load_frag_bf16(xp + k0);
            short8 b0 = load_frag_bf16(yp + k0);
            short8 a1 = load_frag_bf16(xp + k0 + 32);
            short8 b1 = load_frag_bf16(yp + k0 + 32);
            acc0 = __builtin_amdgcn_mfma_f32_16x16x32_bf16(a0, b0, acc0, 0, 0, 0);
            acc1 = __builtin_amdgcn_mfma_f32_16x16x32_bf16(a1, b1, acc1, 0, 0, 0);
        }
        f32x4 acc = acc0 + acc1;

        // C/D layout: col = lane&15, row = (lane>>4)*4 + reg   [measured m89/m91]
        const int ccol = lane & 15;
        const int crow = (lane >> 4) * 4;
        #pragma unroll
        for (int r = 0; r < 4; r++)
            C[(size_t)(m0 + crow + r) * RH + n0 + ccol] = acc[r];
    } else {
        // gates: one wave per j
        const int j = (b - 256) * 4 + w;
        const int tj = target[j];
        const float* e1 = en + (size_t)tj * HH;  // en_l row
        const float* e2 = en + (size_t)j * HH;
        const int h0 = lane * 16;
        float acc = 0.f;
        #pragma unroll
        for (int q = 0; q < 4; q++) {
            f32x4 a  = *reinterpret_cast<const f32x4*>(e1 + h0 + q * 4);
            f32x4 g1 = *reinterpret_cast<const f32x4*>(Wg + h0 + q * 4);
            acc += a.x * g1.x + a.y * g1.y + a.z * g1.z + a.w * g1.w;
            f32x4 c2 = *reinterpret_cast<const f32x4*>(e2 + h0 + q * 4);
            f32x4 g2 = *reinterpret_cast<const f32x4*>(Wg + HH + h0 + q * 4);
            acc += c2.x * g2.x + c2.y * g2.y + c2.z * g2.z + c2.w * g2.w;
        }
        #pragma unroll
        for (int off = 32; off > 0; off >>= 1)
            acc += __shfl_down(acc, off, 64);
        if (lane == 0)
            gates[j] = 1.f / (1.f + __expf(-acc));
    }
}

// att[i,j] = sum_r relu(A[j,r] + c[i,j]*A[t[j],r] + wd[i,r]) * V[r]
// 1024 blocks; block = 8x8 (i,j) tile. Thread: o = output idx (w*16 | lane&15),
// q = lane>>4 selects a 128-wide r-chunk. Reduce across q via shfl_xor(16,32).
__global__ __launch_bounds__(256) void att_kernel(
    const float* __restrict__ A, const float* __restrict__ wd,
    const float* __restrict__ gates, const int* __restrict__ target,
    const float* __restrict__ mask, const float* __restrict__ V,
    float* __restrict__ out)
{
    const int b = blockIdx.x;
    const int i0 = (b >> 5) << 3;
    const int j0 = (b & 31) << 3;
    const int t = threadIdx.x;
    const int w = t >> 6;
    const int l = t & 63;
    const int o = (w << 4) | (l & 15);   // 0..63 output within 8x8 tile
    const int q = l >> 4;                // 0..3 r-chunk
    const int i = i0 + (o >> 3);
    const int j = j0 + (o & 7);
    const int tj = target[j];
    const float c = mask[i * SS + j] * gates[j];

    const f32x4* Ar = reinterpret_cast<const f32x4*>(A + (size_t)j * RH) + q * 32;
    const f32x4* Br = reinterpret_cast<const f32x4*>(A + (size_t)tj * RH) + q * 32;
    const f32x4* Wr = reinterpret_cast<const f32x4*>(wd + (size_t)i * RH) + q * 32;
    const f32x4* Vr = reinterpret_cast<const f32x4*>(V) + q * 32;

    float acc = 0.f;
    #pragma unroll 8
    for (int s = 0; s < 32; s++) {
        f32x4 a  = Ar[s];
        f32x4 bb = Br[s];
        f32x4 ww = Wr[s];
        f32x4 vv = Vr[s];
        acc += fmaxf(fmaf(c, bb.x, a.x) + ww.x, 0.f) * vv.x;
        acc += fmaxf(fmaf(c, bb.y, a.y) + ww.y, 0.f) * vv.y;
        acc += fmaxf(fmaf(c, bb.z, a.z) + ww.z, 0.f) * vv.z;
        acc += fmaxf(fmaf(c, bb.w, a.w) + ww.w, 0.f) * vv.w;
    }
    // reduce the 4 r-chunks: lanes differing in bits 4 and 5 share the same o
    acc += __shfl_xor(acc, 16, 64);
    acc += __shfl_xor(acc, 32, 64);
    if (q == 0)
        out[i * SS + j] = acc;
}

extern "C" void kernel_launch(void* const* d_in, const int* in_sizes, int n_in,
                              void* d_out, int out_size, void* d_ws, size_t ws_size,
                              hipStream_t stream) {
    const float* en     = (const float*)d_in[0];   // (1,256,1024)
    const float* de     = (const float*)d_in[1];   // (1,256,512)
    const int*   target = (const int*)  d_in[2];   // (256,)
    const float* mask_  = (const float*)d_in[3];   // (256,256)
    const float* W1     = (const float*)d_in[4];   // (512,1024)
    const float* W2     = (const float*)d_in[5];   // (512,512)
    const float* V      = (const float*)d_in[6];   // (512,)
    const float* Wg     = (const float*)d_in[7];   // (2048,)
    float* out = (float*)d_out;                    // (1,256,256)

    float* A     = (float*)d_ws;                   // 256*512 f32
    float* wd    = A + SS * RH;                    // 256*512 f32
    float* gates = wd + SS * RH;                   // 256 f32

    prep_kernel<<<320, 256, 0, stream>>>(en, de, target, W1, W2, Wg, A, wd, gates);
    att_kernel<<<1024, 256, 0, stream>>>(A, wd, gates, target, mask_, V, out);
}

// Round 4
// 93.449 us; speedup vs baseline: 1.5334x; 1.2936x over previous
//
#include <hip/hip_runtime.h>

#define SS 256
#define HH 1024
#define RH 512

typedef __attribute__((ext_vector_type(8))) short short8;
typedef __attribute__((ext_vector_type(4))) float f32x4;

// Convert 8 contiguous f32 -> 8 bf16 (packed, RNE) for an MFMA fragment.
__device__ __forceinline__ short8 load_frag_bf16(const float* p) {
    f32x4 lo = *reinterpret_cast<const f32x4*>(p);
    f32x4 hi = *reinterpret_cast<const f32x4*>(p + 4);
    union { int i[4]; short8 s; } u;
    asm("v_cvt_pk_bf16_f32 %0, %1, %2" : "=v"(u.i[0]) : "v"(lo.x), "v"(lo.y));
    asm("v_cvt_pk_bf16_f32 %0, %1, %2" : "=v"(u.i[1]) : "v"(lo.z), "v"(lo.w));
    asm("v_cvt_pk_bf16_f32 %0, %1, %2" : "=v"(u.i[2]) : "v"(hi.x), "v"(hi.y));
    asm("v_cvt_pk_bf16_f32 %0, %1, %2" : "=v"(u.i[3]) : "v"(hi.z), "v"(hi.w));
    return u.s;
}

// Roles by blockIdx.x:
//   [0,128):   A  = en @ W1^T (M=256,N=512,K=1024), 32x32 block tile, 16x16/wave
//   [128,256): wd = de @ W2^T (M=256,N=512,K=512),  same tiling
//   [256,320): gates[j] = sigmoid(concat(e[t[j]], e[j]) . Wg), wave-per-j
__global__ __launch_bounds__(256) void prep_kernel(
    const float* __restrict__ en, const float* __restrict__ de,
    const int* __restrict__ target, const float* __restrict__ W1,
    const float* __restrict__ W2, const float* __restrict__ Wg,
    float* __restrict__ Aout, float* __restrict__ wdout,
    float* __restrict__ gates)
{
    const int b = blockIdx.x;
    const int tid = threadIdx.x;
    const int w = tid >> 6;
    const int lane = tid & 63;

    if (b < 256) {
        const float* X; const float* Y; float* C; int K; int tb;
        if (b < 128) { X = en; Y = W1; C = Aout;  K = HH; tb = b; }
        else         { X = de; Y = W2; C = wdout; K = RH; tb = b - 128; }
        // 32x32 block tile: 8 (M) x 16 (N) block-tiles; wave = 16x16 quadrant
        const int m0 = (tb >> 4) * 32 + (w >> 1) * 16;
        const int n0 = (tb & 15) * 32 + (w & 1) * 16;
        const int fr = lane & 15;          // row within 16-row panel
        const int kf = (lane >> 4) * 8;    // k offset of this lane's 8 elems

        const float* xp = X + (size_t)(m0 + fr) * K + kf;
        const float* yp = Y + (size_t)(n0 + fr) * K + kf;

        f32x4 acc0 = {0.f, 0.f, 0.f, 0.f};
        f32x4 acc1 = {0.f, 0.f, 0.f, 0.f};
        #pragma unroll 4
        for (int k0 = 0; k0 < K; k0 += 64) {
            short8 a0 = load_frag_bf16(xp + k0);
            short8 b0 = load_frag_bf16(yp + k0);
            short8 a1 = load_frag_bf16(xp + k0 + 32);
            short8 b1 = load_frag_bf16(yp + k0 + 32);
            acc0 = __builtin_amdgcn_mfma_f32_16x16x32_bf16(a0, b0, acc0, 0, 0, 0);
            acc1 = __builtin_amdgcn_mfma_f32_16x16x32_bf16(a1, b1, acc1, 0, 0, 0);
        }
        f32x4 acc = acc0 + acc1;

        // C/D layout: col = lane&15, row = (lane>>4)*4 + reg   [measured m89/m91]
        const int ccol = lane & 15;
        const int crow = (lane >> 4) * 4;
        #pragma unroll
        for (int r = 0; r < 4; r++)
            C[(size_t)(m0 + crow + r) * RH + n0 + ccol] = acc[r];
    } else {
        // gates: one wave per j
        const int j = (b - 256) * 4 + w;
        const int tj = target[j];
        const float* e1 = en + (size_t)tj * HH;  // en_l row
        const float* e2 = en + (size_t)j * HH;
        const int h0 = lane * 16;
        float acc = 0.f;
        #pragma unroll
        for (int q = 0; q < 4; q++) {
            f32x4 a  = *reinterpret_cast<const f32x4*>(e1 + h0 + q * 4);
            f32x4 g1 = *reinterpret_cast<const f32x4*>(Wg + h0 + q * 4);
            acc += a.x * g1.x + a.y * g1.y + a.z * g1.z + a.w * g1.w;
            f32x4 c2 = *reinterpret_cast<const f32x4*>(e2 + h0 + q * 4);
            f32x4 g2 = *reinterpret_cast<const f32x4*>(Wg + HH + h0 + q * 4);
            acc += c2.x * g2.x + c2.y * g2.y + c2.z * g2.z + c2.w * g2.w;
        }
        #pragma unroll
        for (int off = 32; off > 0; off >>= 1)
            acc += __shfl_down(acc, off, 64);
        if (lane == 0)
            gates[j] = 1.f / (1.f + __expf(-acc));
    }
}

// att[i,j] = sum_r relu(A[j,r] + c[i,j]*A[t[j],r] + wd[i,r]) * V[r]
// Block = 512 threads = 8 waves; wave owns one j, block covers 32 i's.
// Lane l owns r in [l*8, l*8+8): A[j], A[tj], V live in registers (coalesced,
// loaded once). Inner loop streams wd rows (coalesced 2KB wave-loads).
// c is lane-uniform per i -> one __shfl broadcast; r-reduce = 6-step butterfly.
__global__ __launch_bounds__(512) void att_kernel(
    const float* __restrict__ A, const float* __restrict__ wd,
    const float* __restrict__ gates, const int* __restrict__ target,
    const float* __restrict__ mask, const float* __restrict__ V,
    float* __restrict__ out)
{
    const int b = blockIdx.x;
    const int i0 = (b >> 5) << 5;                         // 8 i-groups of 32
    const int j  = ((b & 31) << 3) + (threadIdx.x >> 6);  // wave -> j
    const int l  = threadIdx.x & 63;

    const int   tj = target[j];
    const float gj = gates[j];

    const float* Ar = A + (size_t)j  * RH + l * 8;
    const float* Br = A + (size_t)tj * RH + l * 8;
    const f32x4 a0 = *reinterpret_cast<const f32x4*>(Ar);
    const f32x4 a1 = *reinterpret_cast<const f32x4*>(Ar + 4);
    const f32x4 b0 = *reinterpret_cast<const f32x4*>(Br);
    const f32x4 b1 = *reinterpret_cast<const f32x4*>(Br + 4);
    const f32x4 v0 = *reinterpret_cast<const f32x4*>(V + l * 8);
    const f32x4 v1 = *reinterpret_cast<const f32x4*>(V + l * 8 + 4);

    // lane l (l<32 meaningful) holds mask[i0+l, j] * g[j]
    const float mval = mask[(i0 + (l & 31)) * SS + j] * gj;

    const float* wp = wd + (size_t)i0 * RH + l * 8;
    float keep = 0.f;
    #pragma unroll 4
    for (int ii = 0; ii < 32; ii++) {
        const float c = __shfl(mval, ii, 64);
        const f32x4 w0 = *reinterpret_cast<const f32x4*>(wp);
        const f32x4 w1 = *reinterpret_cast<const f32x4*>(wp + 4);
        wp += RH;
        float p;
        p  = fmaxf(fmaf(c, b0.x, a0.x) + w0.x, 0.f) * v0.x;
        p += fmaxf(fmaf(c, b0.y, a0.y) + w0.y, 0.f) * v0.y;
        p += fmaxf(fmaf(c, b0.z, a0.z) + w0.z, 0.f) * v0.z;
        p += fmaxf(fmaf(c, b0.w, a0.w) + w0.w, 0.f) * v0.w;
        p += fmaxf(fmaf(c, b1.x, a1.x) + w1.x, 0.f) * v1.x;
        p += fmaxf(fmaf(c, b1.y, a1.y) + w1.y, 0.f) * v1.y;
        p += fmaxf(fmaf(c, b1.z, a1.z) + w1.z, 0.f) * v1.z;
        p += fmaxf(fmaf(c, b1.w, a1.w) + w1.w, 0.f) * v1.w;
        // butterfly reduce across 64 lanes
        p += __shfl_xor(p, 32, 64);
        p += __shfl_xor(p, 16, 64);
        p += __shfl_xor(p,  8, 64);
        p += __shfl_xor(p,  4, 64);
        p += __shfl_xor(p,  2, 64);
        p += __shfl_xor(p,  1, 64);
        keep = (l == ii) ? p : keep;   // collect result ii in lane ii
    }
    if (l < 32)
        out[(size_t)(i0 + l) * SS + j] = keep;
}

extern "C" void kernel_launch(void* const* d_in, const int* in_sizes, int n_in,
                              void* d_out, int out_size, void* d_ws, size_t ws_size,
                              hipStream_t stream) {
    const float* en     = (const float*)d_in[0];   // (1,256,1024)
    const float* de     = (const float*)d_in[1];   // (1,256,512)
    const int*   target = (const int*)  d_in[2];   // (256,)
    const float* mask_  = (const float*)d_in[3];   // (256,256)
    const float* W1     = (const float*)d_in[4];   // (512,1024)
    const float* W2     = (const float*)d_in[5];   // (512,512)
    const float* V      = (const float*)d_in[6];   // (512,)
    const float* Wg     = (const float*)d_in[7];   // (2048,)
    float* out = (float*)d_out;                    // (1,256,256)

    float* A     = (float*)d_ws;                   // 256*512 f32
    float* wd    = A + SS * RH;                    // 256*512 f32
    float* gates = wd + SS * RH;                   // 256 f32

    prep_kernel<<<320, 256, 0, stream>>>(en, de, target, W1, W2, Wg, A, wd, gates);
    att_kernel<<<256, 512, 0, stream>>>(A, wd, gates, target, mask_, V, out);
}